// Round 5
// baseline (446.950 us; speedup 1.0000x reference)
//
#include <hip/hip_runtime.h>

// Round 5: dispatch count 19->12 (batched converts/transposes), FFN2 split-K=4
// at 8 blocks/CU, KV & FFN1 to 64x128 tiles (4/8 blocks/CU). LN combines N
// split-K partials.

typedef unsigned short u16;
typedef __attribute__((ext_vector_type(8))) short bvec8;   // 8 bf16 (4 VGPRs)
typedef __attribute__((ext_vector_type(4))) float fvec4;

#define MFMA16(a, b, c) __builtin_amdgcn_mfma_f32_16x16x32_bf16((a), (b), (c), 0, 0, 0)

__device__ __forceinline__ u16 f2b(float f) {
  union { float f; unsigned u; } x; x.f = f;
  unsigned u = x.u;
  return (u16)((u + 0x7FFFu + ((u >> 16) & 1u)) >> 16);  // RNE
}
__device__ __forceinline__ u16 f2b_t(float f) {  // truncate (cheap, for P only)
  union { float f; unsigned u; } x; x.f = f;
  return (u16)(x.u >> 16);
}
// async global->LDS, 16B/lane; LDS dest = wave-uniform base + lane*16
__device__ __forceinline__ void gl_lds16(const u16* g, u16* lds) {
  __builtin_amdgcn_global_load_lds(
      (const __attribute__((address_space(1))) void*)g,
      (__attribute__((address_space(3))) void*)lds, 16, 0, 0);
}

// ------------- fused fp32->bf16 for tgt+mem (one launch) ----------------
__global__ __launch_bounds__(256) void k_prep(const float* __restrict__ tgt,
                                              const float* __restrict__ mem,
                                              u16* __restrict__ tgt_b,
                                              u16* __restrict__ mem_b) {
  int bx = blockIdx.x;
  const float* in = (bx < 4096) ? tgt : mem;
  u16* out = (bx < 4096) ? tgt_b : mem_b;
  int i = (bx & 4095) * 256 + threadIdx.x;
  float4 v = ((const float4*)in)[i];
  ushort4 o;
  o.x = f2b(v.x); o.y = f2b(v.y); o.z = f2b(v.z); o.w = f2b(v.w);
  ((ushort4*)out)[i] = o;
}

// ------------- batched W[K][N] fp32 -> WT[N][K] bf16 (all 6 weights) --------
__global__ __launch_bounds__(256) void k_wtb(
    const float* __restrict__ wq, const float* __restrict__ wk,
    const float* __restrict__ wv, const float* __restrict__ wo,
    const float* __restrict__ w1, const float* __restrict__ w2,
    u16* __restrict__ wqT, u16* __restrict__ wkvT, u16* __restrict__ woT,
    u16* __restrict__ w1T, u16* __restrict__ w2T) {
  __shared__ float t[32][33];
  int b = blockIdx.x;
  const float* W; u16* WT; int K, N, bx, by;
  if (b < 4096) {            // wq/wk/wv/wo: 1024x1024, 1024 tiles each
    int m = b >> 10, tt = b & 1023;
    bx = tt & 31; by = tt >> 5; K = 1024; N = 1024;
    W = (m == 0) ? wq : (m == 1) ? wk : (m == 2) ? wv : wo;
    WT = (m == 0) ? wqT : (m == 1) ? wkvT : (m == 2) ? wkvT + 1024 * 1024 : woT;
  } else if (b < 8192) {     // w1: K=1024, N=4096
    int tt = b - 4096; bx = tt & 127; by = tt >> 7; K = 1024; N = 4096;
    W = w1; WT = w1T;
  } else {                   // w2: K=4096, N=1024
    int tt = b - 8192; bx = tt & 31; by = tt >> 5; K = 4096; N = 1024;
    W = w2; WT = w2T;
  }
  int tx = threadIdx.x & 31, ty = threadIdx.x >> 5;
  int n0 = bx * 32, k0 = by * 32;
#pragma unroll
  for (int i = 0; i < 4; i++)
    t[ty + i * 8][tx] = W[(size_t)(k0 + ty + i * 8) * N + n0 + tx];
  __syncthreads();
#pragma unroll
  for (int i = 0; i < 4; i++)
    WT[(size_t)(n0 + ty + i * 8) * K + k0 + tx] = f2b(t[tx][ty + i * 8]);
}

// ---------------- V[b*2048+s][h*64+d] bf16 -> Vt[bh][d][s] ----------------
__global__ __launch_bounds__(256) void k_vt(const u16* __restrict__ V,
                                            u16* __restrict__ Vt) {
  __shared__ u16 t[32][33];
  int tx = threadIdx.x & 31, ty = threadIdx.x >> 5;
  int s0 = blockIdx.x * 32, d0 = blockIdx.y * 32, bh = blockIdx.z;
  int b = bh >> 4, h = bh & 15;
#pragma unroll
  for (int i = 0; i < 4; i++)
    t[ty + i * 8][tx] = V[(size_t)(b * 2048 + s0 + ty + i * 8) * 1024 + h * 64 + d0 + tx];
  __syncthreads();
#pragma unroll
  for (int i = 0; i < 4; i++)
    Vt[((size_t)bh * 64 + d0 + ty + i * 8) * 2048 + s0 + tx] = t[tx][ty + i * 8];
}

// ---------------- templated MFMA GEMM: C[M][N] = A[M][K] @ BT[N][K]^T --------
// Tile TM x TN (2x2 wave grid), BK=32, global_load_lds w=16, rotate-swizzle.
// Split-K via gridDim.z: block z covers K rows [z*Klen, (z+1)*Klen); Kstride is
// the full row stride. flags: 1=relu, 2=bf16 outB, 4=fp32 outF, 8=add resid,
// 16=raw split-K partial (acc -> outF + z*M*N, no bias/scale/relu/resid).
// Dual-output (outB2 != null): col<1024 -> outB/bias, col>=1024 -> outB2/bias2.
template <int TM, int TN>
__global__ __launch_bounds__(256, TM == 64 ? 4 : 3) void k_gemm(
    const u16* __restrict__ A, const u16* __restrict__ BT,
    const float* __restrict__ bias, const float* __restrict__ bias2,
    const float* __restrict__ resid, float* __restrict__ outF,
    u16* __restrict__ outB, u16* __restrict__ outB2,
    int M, int N, int Kstride, int Klen, float scale, int flags) {
  constexpr int WM = TM / 2, WN = TN / 2;
  constexpr int MI = WM / 16, NI = WN / 16;
  constexpr int NCALL = (TM + TN) / 64;  // 16-row staging calls per wave
  __shared__ u16 S[(TM + TN) * 32];      // A rows [0,TM), B rows [TM,TM+TN)
  const int tid = threadIdx.x, w = tid >> 6, lane = tid & 63;
  const int q = lane >> 4, l = lane & 15;
  const int m0 = blockIdx.y * TM, n0 = blockIdx.x * TN;
  const int kbeg = blockIdx.z * Klen;
  const int wm = (w >> 1) * WM, wn = (w & 1) * WN;
  // staging: call c covers tile rows [(w*NCALL+c)*16, +16); lane i -> row +i>>2,
  // col group rotated by (row>>1)&3. Global side permuted, LDS linear.
  const int srow = lane >> 2, sgrp = lane & 3;
  const int gcol = ((sgrp + (srow >> 1)) & 3) * 8;
  // frag read: row = base+16i+l -> rot=(l>>1)&3; LDS pos holding k-group q:
  const int rpos = ((q + 4 - ((l >> 1) & 3)) & 3) * 8;
  const u16* gp[NCALL];
  u16* lp[NCALL];
#pragma unroll
  for (int c = 0; c < NCALL; c++) {
    int r0 = (w * NCALL + c) * 16;
    gp[c] = (r0 < TM) ? A + (size_t)(m0 + r0 + srow) * Kstride + kbeg + gcol
                      : BT + (size_t)(n0 + r0 - TM + srow) * Kstride + kbeg + gcol;
    lp[c] = &S[r0 * 32];
  }
  fvec4 acc[MI][NI] = {};
#pragma unroll 1
  for (int k0 = 0; k0 < Klen; k0 += 32) {
#pragma unroll
    for (int c = 0; c < NCALL; c++) gl_lds16(gp[c] + k0, lp[c]);
    __syncthreads();
    bvec8 af[MI], bf[NI];
#pragma unroll
    for (int i = 0; i < MI; i++)
      af[i] = *(const bvec8*)&S[(wm + 16 * i + l) * 32 + rpos];
#pragma unroll
    for (int j = 0; j < NI; j++)
      bf[j] = *(const bvec8*)&S[(TM + wn + 16 * j + l) * 32 + rpos];
#pragma unroll
    for (int i = 0; i < MI; i++)
#pragma unroll
      for (int j = 0; j < NI; j++)
        acc[i][j] = MFMA16(af[i], bf[j], acc[i][j]);
    __syncthreads();
  }
  if (flags & 16) {  // raw split-K partial
    float* po = outF + (size_t)blockIdx.z * M * N;
#pragma unroll
    for (int mi = 0; mi < MI; mi++)
#pragma unroll
      for (int ni = 0; ni < NI; ni++) {
        int row = m0 + wm + mi * 16 + q * 4;
        int col = n0 + wn + ni * 16 + l;
#pragma unroll
        for (int r = 0; r < 4; r++)
          po[(size_t)(row + r) * N + col] = acc[mi][ni][r];
      }
    return;
  }
  const int On = outB2 ? 1024 : N;
#pragma unroll
  for (int mi = 0; mi < MI; mi++)
#pragma unroll
    for (int ni = 0; ni < NI; ni++) {
      int row = m0 + wm + mi * 16 + q * 4;
      int col = n0 + wn + ni * 16 + l;
      const float* bs = bias;
      u16* ob = outB;
      float sc = scale;
      int oc = col;
      if (outB2 && col >= 1024) { bs = bias2; ob = outB2; sc = 1.0f; oc = col - 1024; }
      float bv = bs[oc];
#pragma unroll
      for (int r = 0; r < 4; r++) {
        float v = (acc[mi][ni][r] + bv) * sc;
        if (flags & 1) v = fmaxf(v, 0.0f);
        size_t idx = (size_t)(row + r) * On + oc;
        if (flags & 8) v += resid[idx];
        if (flags & 2) ob[idx] = f2b(v);
        if (flags & 4) outF[idx] = v;
      }
    }
}

// ---------------- block-cooperative no-max flash attention, s-split ----------
// grid (512, 2): x = 32 bh * 16 t-blocks, y = s-split (1024 s each; exact since
// no-max softmax is linear in s). Emits unnormalized fp32 o-partials + l-sums.
__global__ __launch_bounds__(256, 4) void k_attn(
    const u16* __restrict__ Q, const u16* __restrict__ Kb,
    const u16* __restrict__ Vt, float* __restrict__ opart,
    float* __restrict__ lpart) {
  __shared__ u16 Ks[64 * 64];        // [s][d], col groups rotated by s&7
  __shared__ u16 Vs[64 * 64];        // [d][s], col groups rotated by d&7
  __shared__ u16 Ps[4][2][16 * 72];  // per-wave P, stride 72 (16B-aligned, 2-way)
  const int tid = threadIdx.x, w = tid >> 6, lane = tid & 63;
  const int q = lane >> 4, l = lane & 15;
  const int blk = blockIdx.x;
  const int bh = blk >> 4, tb = blk & 15;
  const int b = bh >> 4, h = bh & 15;
  const int t0 = tb * 128 + w * 32;
  const int sbeg = blockIdx.y * 1024;
  float* op = opart + (size_t)blockIdx.y * 4096 * 1024;
  float* lp = lpart + (size_t)blockIdx.y * 4096 * 16;
  const u16* Qp = Q + (size_t)(b * 2048 + t0) * 1024 + h * 64;
  const u16* Kp = Kb + (size_t)(b * 2048) * 1024 + h * 64;
  const u16* Vp = Vt + (size_t)bh * 64 * 2048;
  // staging lane geometry: 1KB/call = 8 rows x 128B; lane i -> row i>>3, group i&7
  const int rowin = lane >> 3, grp = lane & 7;
  const int gcol = ((grp + rowin) & 7) * 8;
  // frag-read LDS col offsets (rotation by row&7 == l&7, loop-invariant):
  const int kc0 = ((q + 8 - (l & 7)) & 7) * 8;       // k-group q
  const int kc1 = ((q + 12 - (l & 7)) & 7) * 8;      // k-group q+4
  bvec8 aQ[2][2];
#pragma unroll
  for (int ti = 0; ti < 2; ti++)
#pragma unroll
    for (int kh = 0; kh < 2; kh++)
      aQ[ti][kh] = *(const bvec8*)&Qp[(size_t)(ti * 16 + l) * 1024 + kh * 32 + q * 8];
  fvec4 o[2][4] = {};
  float ls[2][4] = {};
#pragma unroll 1
  for (int s0 = sbeg; s0 < sbeg + 1024; s0 += 64) {
    gl_lds16(Kp + (size_t)(s0 + w * 8 + rowin) * 1024 + gcol, &Ks[(w * 8) * 64]);
    gl_lds16(Kp + (size_t)(s0 + 32 + w * 8 + rowin) * 1024 + gcol, &Ks[(32 + w * 8) * 64]);
    gl_lds16(Vp + (size_t)(w * 8 + rowin) * 2048 + s0 + gcol, &Vs[(w * 8) * 64]);
    gl_lds16(Vp + (size_t)(32 + w * 8 + rowin) * 2048 + s0 + gcol, &Vs[(32 + w * 8) * 64]);
    __syncthreads();  // compiler drains vmcnt before barrier -> staged data visible
    fvec4 sc[2][4];
#pragma unroll
    for (int ti = 0; ti < 2; ti++)
#pragma unroll
      for (int ss = 0; ss < 4; ss++) sc[ti][ss] = (fvec4){0.f, 0.f, 0.f, 0.f};
#pragma unroll
    for (int ss = 0; ss < 4; ss++) {
      const int ro = (ss * 16 + l) * 64;
      bvec8 kf0 = *(const bvec8*)&Ks[ro + kc0];
      bvec8 kf1 = *(const bvec8*)&Ks[ro + kc1];
#pragma unroll
      for (int ti = 0; ti < 2; ti++) {
        sc[ti][ss] = MFMA16(aQ[ti][0], kf0, sc[ti][ss]);
        sc[ti][ss] = MFMA16(aQ[ti][1], kf1, sc[ti][ss]);
      }
    }
    // exp (no max subtraction; scores ~ N(0,1)) + P write in C-layout position
#pragma unroll
    for (int ti = 0; ti < 2; ti++)
#pragma unroll
      for (int ss = 0; ss < 4; ss++)
#pragma unroll
        for (int r = 0; r < 4; r++) {
          float p = __expf(sc[ti][ss][r]);
          ls[ti][r] += p;
          Ps[w][ti][(q * 4 + r) * 72 + ss * 16 + l] = f2b_t(p);
        }
    asm volatile("s_waitcnt lgkmcnt(0)" ::: "memory");  // P writes -> same-wave reads
    bvec8 bV[4][2];
#pragma unroll
    for (int dt = 0; dt < 4; dt++) {
      const int ro = (dt * 16 + l) * 64;
      bV[dt][0] = *(const bvec8*)&Vs[ro + kc0];
      bV[dt][1] = *(const bvec8*)&Vs[ro + kc1];
    }
#pragma unroll
    for (int ti = 0; ti < 2; ti++) {
      bvec8 aP0 = *(const bvec8*)&Ps[w][ti][l * 72 + q * 8];
      bvec8 aP1 = *(const bvec8*)&Ps[w][ti][l * 72 + 32 + q * 8];
#pragma unroll
      for (int dt = 0; dt < 4; dt++) {
        o[ti][dt] = MFMA16(aP0, bV[dt][0], o[ti][dt]);
        o[ti][dt] = MFMA16(aP1, bV[dt][1], o[ti][dt]);
      }
    }
    __syncthreads();  // all waves done reading Ks/Vs before next stage
  }
#pragma unroll
  for (int ti = 0; ti < 2; ti++)
#pragma unroll
    for (int r = 0; r < 4; r++) {
      float s = ls[ti][r];
      s += __shfl_xor(s, 1, 64);
      s += __shfl_xor(s, 2, 64);
      s += __shfl_xor(s, 4, 64);
      s += __shfl_xor(s, 8, 64);  // sum over the 16 lanes of quad q (rows q*4+r)
      int trow = b * 2048 + t0 + ti * 16 + q * 4 + r;
      if (l == 0) lp[trow * 16 + h] = s;
#pragma unroll
      for (int dt = 0; dt < 4; dt++)
        op[(size_t)trow * 1024 + h * 64 + dt * 16 + l] = o[ti][dt][r];
    }
}

// ---------------- attention combine: ctx = (o0+o1) / (l0+l1) ----------------
__global__ __launch_bounds__(256) void k_actx(const float* __restrict__ opart,
                                              const float* __restrict__ lpart,
                                              u16* __restrict__ ctx) {
  int row = blockIdx.x, c0 = threadIdx.x * 4;
  int h = c0 >> 6;
  float lsum = lpart[row * 16 + h] + lpart[4096 * 16 + row * 16 + h];
  float inv = 1.0f / lsum;
  float4 a = *(const float4*)&opart[(size_t)row * 1024 + c0];
  float4 b = *(const float4*)&opart[(size_t)4096 * 1024 + (size_t)row * 1024 + c0];
  ushort4 o;
  o.x = f2b((a.x + b.x) * inv);
  o.y = f2b((a.y + b.y) * inv);
  o.z = f2b((a.z + b.z) * inv);
  o.w = f2b((a.w + b.w) * inv);
  *(ushort4*)&ctx[(size_t)row * 1024 + c0] = o;
}

// ---- LayerNorm over dim 1024, fused split-K combine: y = Σparts+bias+res ----
__global__ __launch_bounds__(256) void k_lnp(
    const float* __restrict__ parts, int nparts,
    const float* __restrict__ bias, const float* __restrict__ resid,
    const float* __restrict__ g, const float* __restrict__ be,
    float* __restrict__ xf, u16* __restrict__ xb) {
  __shared__ float sm[8];
  int row = blockIdx.x, tid = threadIdx.x;
  size_t base = (size_t)row * 1024;
  const size_t pstride = (size_t)4096 * 1024;
  float v[4], s = 0.f, ss = 0.f;
#pragma unroll
  for (int j = 0; j < 4; j++) {
    int c = tid + j * 256;
    float acc = bias[c] + resid[base + c];
    for (int z = 0; z < nparts; z++) acc += parts[z * pstride + base + c];
    v[j] = acc;
    s += acc; ss += acc * acc;
  }
#pragma unroll
  for (int off = 32; off; off >>= 1) {
    s += __shfl_down(s, off, 64);
    ss += __shfl_down(ss, off, 64);
  }
  int w = tid >> 6;
  if ((tid & 63) == 0) { sm[w] = s; sm[4 + w] = ss; }
  __syncthreads();
  float S = sm[0] + sm[1] + sm[2] + sm[3];
  float SS = sm[4] + sm[5] + sm[6] + sm[7];
  float mean = S * (1.0f / 1024.0f);
  float var = SS * (1.0f / 1024.0f) - mean * mean;
  float rstd = rsqrtf(var + 1e-5f);
#pragma unroll
  for (int j = 0; j < 4; j++) {
    int c = tid + j * 256;
    float o = (v[j] - mean) * rstd * g[c] + be[c];
    xf[base + c] = o;
    if (xb) xb[base + c] = f2b(o);
  }
}

extern "C" void kernel_launch(void* const* d_in, const int* in_sizes, int n_in,
                              void* d_out, int out_size, void* d_ws, size_t ws_size,
                              hipStream_t stream) {
  (void)in_sizes; (void)n_in; (void)out_size; (void)ws_size;
  const float* tgt = (const float*)d_in[0];
  const float* mem = (const float*)d_in[1];
  const float* wq  = (const float*)d_in[2];
  const float* bq  = (const float*)d_in[3];
  const float* wk  = (const float*)d_in[4];
  const float* bk  = (const float*)d_in[5];
  const float* wv  = (const float*)d_in[6];
  const float* bv  = (const float*)d_in[7];
  const float* wo  = (const float*)d_in[8];
  const float* bo  = (const float*)d_in[9];
  const float* w1  = (const float*)d_in[10];
  const float* b1  = (const float*)d_in[11];
  const float* w2  = (const float*)d_in[12];
  const float* b2  = (const float*)d_in[13];
  const float* g1  = (const float*)d_in[14];
  const float* be1 = (const float*)d_in[15];
  const float* g2  = (const float*)d_in[16];
  const float* be2 = (const float*)d_in[17];
  float* out = (float*)d_out;

  char* ws = (char*)d_ws;
  size_t off = 0;
  auto take = [&](size_t bytes) { char* p = ws + off; off += bytes; return p; };
  const size_t MB = 1024 * 1024;
  u16* tgt_b = (u16*)take(8 * MB);    // [4096][1024] bf16
  u16* mem_b = (u16*)take(8 * MB);
  u16* wqT   = (u16*)take(2 * MB);    // [1024][1024]
  u16* wkvT  = (u16*)take(4 * MB);    // [2048][1024]: wk^T then wv^T
  u16* woT   = (u16*)take(2 * MB);
  u16* w1T   = (u16*)take(8 * MB);    // [4096][1024]
  u16* w2T   = (u16*)take(8 * MB);    // [1024][4096]
  u16* Qb    = (u16*)take(8 * MB);
  u16* Kb    = (u16*)take(8 * MB);
  u16* Vb    = (u16*)take(8 * MB);
  u16* Vtb   = (u16*)take(8 * MB);    // [32][64][2048]
  u16* ctx   = (u16*)take(8 * MB);
  float* opart = (float*)take(32 * MB);  // attn o-partials [2][4096][1024] fp32
  float* opj   = (float*)take(32 * MB);  // O-proj split-K partials [2][4096][1024]
  float* lpart = (float*)take(1 * MB);   // attn l-sums [2][4096][16] fp32
  float* xf  = (float*)take(16 * MB);
  u16* xb    = (u16*)take(8 * MB);
  u16* hbuf  = Qb;                    // [4096][4096] bf16 over Qb..Vtb (dead after attn)
  float* fp2 = opart;                 // FFN2 partials [4][4096][1024] over opart+opj
                                      // (both dead after k_actx / LN1)

  // 1. converts + weight transposes (batched: 2 launches)
  k_prep<<<8192, 256, 0, stream>>>(tgt, mem, tgt_b, mem_b);
  k_wtb<<<12288, 256, 0, stream>>>(wq, wk, wv, wo, w1, w2,
                                   wqT, wkvT, woT, w1T, w2T);
  // 2. Q proj (scale 1/sqrt(64) folded): 64x128, 512 blocks
  k_gemm<64, 128><<<dim3(8, 64), 256, 0, stream>>>(
      tgt_b, wqT, bq, nullptr, nullptr, nullptr, Qb, nullptr,
      4096, 1024, 1024, 1024, 0.125f, 2);
  // 3. fused K+V proj (dual-output): 64x128, 1024 blocks -> 4 blk/CU
  k_gemm<64, 128><<<dim3(16, 64), 256, 0, stream>>>(
      mem_b, wkvT, bk, bv, nullptr, nullptr, Kb, Vb,
      4096, 2048, 1024, 1024, 1.0f, 2);
  k_vt<<<dim3(64, 2, 32), 256, 0, stream>>>(Vb, Vtb);
  // 4. attention, s-split=2 -> 1024 blocks, 4 blk/CU
  k_attn<<<dim3(512, 2), 256, 0, stream>>>(Qb, Kb, Vtb, opart, lpart);
  k_actx<<<4096, 256, 0, stream>>>(opart, lpart, ctx);
  // 5. O-proj split-K=2 raw partials -> opj, 1024 blocks
  k_gemm<64, 128><<<dim3(8, 64, 2), 256, 0, stream>>>(
      ctx, woT, nullptr, nullptr, nullptr, opj, nullptr, nullptr,
      4096, 1024, 1024, 512, 1.0f, 16);
  // 6. LN1 fused combine: y = opj0+opj1+bo+tgt
  k_lnp<<<4096, 256, 0, stream>>>(opj, 2, bo, tgt, g1, be1, xf, xb);
  // 7. FFN1: relu(x @ w1 + b1), 64x128, 2048 blocks -> 8 blk/CU
  k_gemm<64, 128><<<dim3(32, 64), 256, 0, stream>>>(
      xb, w1T, b1, nullptr, nullptr, nullptr, hbuf, nullptr,
      4096, 4096, 1024, 1024, 1.0f, 1 | 2);
  // 8. FFN2 split-K=4 raw partials -> fp2, 2048 blocks -> 8 blk/CU
  k_gemm<64, 128><<<dim3(8, 64, 4), 256, 0, stream>>>(
      hbuf, w2T, nullptr, nullptr, nullptr, fp2, nullptr, nullptr,
      4096, 1024, 4096, 1024, 1.0f, 16);
  // 9. LN2 fused combine: y = Σfp2 + b2 + xf
  k_lnp<<<4096, 256, 0, stream>>>(fp2, 4, b2, xf, g2, be2, out, nullptr);
}

// Round 7
// 403.797 us; speedup vs baseline: 1.1069x; 1.1069x over previous
//
#include <hip/hip_runtime.h>

// Round 6b (compile fix): revert r5 tile regressions (FFN2 split-K=2, KV/FFN1
// at 128x128 = r4 measured-best), cut dispatches 12->9: k_pre merges converts+
// transposes, k_qkv merges Q-proj+KV-proj with V-transpose fused into epilogue.

typedef unsigned short u16;
typedef __attribute__((ext_vector_type(8))) short bvec8;   // 8 bf16 (4 VGPRs)
typedef __attribute__((ext_vector_type(4))) float fvec4;

#define MFMA16(a, b, c) __builtin_amdgcn_mfma_f32_16x16x32_bf16((a), (b), (c), 0, 0, 0)

__device__ __forceinline__ u16 f2b(float f) {
  union { float f; unsigned u; } x; x.f = f;
  unsigned u = x.u;
  return (u16)((u + 0x7FFFu + ((u >> 16) & 1u)) >> 16);  // RNE
}
__device__ __forceinline__ u16 f2b_t(float f) {  // truncate (cheap, for P only)
  union { float f; unsigned u; } x; x.f = f;
  return (u16)(x.u >> 16);
}
// async global->LDS, 16B/lane; LDS dest = wave-uniform base + lane*16
__device__ __forceinline__ void gl_lds16(const u16* g, u16* lds) {
  __builtin_amdgcn_global_load_lds(
      (const __attribute__((address_space(1))) void*)g,
      (__attribute__((address_space(3))) void*)lds, 16, 0, 0);
}

// ------- merged prep: fp32->bf16 converts (blocks 0..8191) + all weight
// ------- transposes W[K][N] -> WT[N][K] bf16 (blocks 8192..20479) ----------
__global__ __launch_bounds__(256) void k_pre(
    const float* __restrict__ tgt, const float* __restrict__ mem,
    const float* __restrict__ wq, const float* __restrict__ wk,
    const float* __restrict__ wv, const float* __restrict__ wo,
    const float* __restrict__ w1, const float* __restrict__ w2,
    u16* __restrict__ tgt_b, u16* __restrict__ mem_b,
    u16* __restrict__ wqT, u16* __restrict__ wkvT, u16* __restrict__ woT,
    u16* __restrict__ w1T, u16* __restrict__ w2T) {
  __shared__ float t[32][33];
  int bb = blockIdx.x;
  if (bb < 8192) {  // activation converts
    const float* in = (bb < 4096) ? tgt : mem;
    u16* outp = (bb < 4096) ? tgt_b : mem_b;
    int i = (bb & 4095) * 256 + threadIdx.x;
    float4 v = ((const float4*)in)[i];
    ushort4 o;
    o.x = f2b(v.x); o.y = f2b(v.y); o.z = f2b(v.z); o.w = f2b(v.w);
    ((ushort4*)outp)[i] = o;
    return;
  }
  int b = bb - 8192;
  const float* W; u16* WT; int K, N, bx, by;
  if (b < 4096) {            // wq/wk/wv/wo: 1024x1024, 1024 tiles each
    int m = b >> 10, tt = b & 1023;
    bx = tt & 31; by = tt >> 5; K = 1024; N = 1024;
    W = (m == 0) ? wq : (m == 1) ? wk : (m == 2) ? wv : wo;
    WT = (m == 0) ? wqT : (m == 1) ? wkvT : (m == 2) ? wkvT + 1024 * 1024 : woT;
  } else if (b < 8192) {     // w1: K=1024, N=4096
    int tt = b - 4096; bx = tt & 127; by = tt >> 7; K = 1024; N = 4096;
    W = w1; WT = w1T;
  } else {                   // w2: K=4096, N=1024
    int tt = b - 8192; bx = tt & 31; by = tt >> 5; K = 4096; N = 1024;
    W = w2; WT = w2T;
  }
  int tx = threadIdx.x & 31, ty = threadIdx.x >> 5;
  int n0 = bx * 32, k0 = by * 32;
#pragma unroll
  for (int i = 0; i < 4; i++)
    t[ty + i * 8][tx] = W[(size_t)(k0 + ty + i * 8) * N + n0 + tx];
  __syncthreads();
#pragma unroll
  for (int i = 0; i < 4; i++)
    WT[(size_t)(n0 + ty + i * 8) * K + k0 + tx] = f2b(t[tx][ty + i * 8]);
}

// ------- merged Q-proj + KV-proj, 128x128 tiles, V-transpose fused ----------
// blocks 0..255: Q = (tgt_b @ wqT^T + bq)*0.125 -> Qb bf16
// blocks 256..767: KV = mem_b @ wkvT^T; col<1024 -> Kb (+bk); col>=1024 ->
//   Vt[bh][d][s] (+bv) via packed 8B stores (4 r-values = 4 consecutive s).
__global__ __launch_bounds__(256, 3) void k_qkv(
    const u16* __restrict__ tgt_b, const u16* __restrict__ mem_b,
    const u16* __restrict__ wqT, const u16* __restrict__ wkvT,
    const float* __restrict__ bq, const float* __restrict__ bk,
    const float* __restrict__ bv,
    u16* __restrict__ Qb, u16* __restrict__ Kb, u16* __restrict__ Vtb) {
  __shared__ u16 S[256 * 32];
  const int tid = threadIdx.x, w = tid >> 6, lane = tid & 63;
  const int q = lane >> 4, l = lane & 15;
  const bool isQ = blockIdx.x < 256;
  const int id = isQ ? blockIdx.x : blockIdx.x - 256;
  const int nx = isQ ? 8 : 16;
  const int m0 = (id / nx) * 128, n0 = (id % nx) * 128;
  const u16* A = isQ ? tgt_b : mem_b;
  const u16* BT = isQ ? wqT : wkvT;
  const int wm = (w >> 1) * 64, wn = (w & 1) * 64;
  const int srow = lane >> 2, sgrp = lane & 3;
  const int gcol = ((sgrp + (srow >> 1)) & 3) * 8;
  const int rpos = ((q + 4 - ((l >> 1) & 3)) & 3) * 8;
  const u16* gp[4];
  u16* lp[4];
#pragma unroll
  for (int c = 0; c < 4; c++) {
    int r0 = (w * 4 + c) * 16;
    gp[c] = (r0 < 128) ? A + (size_t)(m0 + r0 + srow) * 1024 + gcol
                       : BT + (size_t)(n0 + r0 - 128 + srow) * 1024 + gcol;
    lp[c] = &S[r0 * 32];
  }
  fvec4 acc[4][4] = {};
#pragma unroll 1
  for (int k0 = 0; k0 < 1024; k0 += 32) {
#pragma unroll
    for (int c = 0; c < 4; c++) gl_lds16(gp[c] + k0, lp[c]);
    __syncthreads();
    bvec8 af[4], bf[4];
#pragma unroll
    for (int i = 0; i < 4; i++) {
      af[i] = *(const bvec8*)&S[(wm + 16 * i + l) * 32 + rpos];
      bf[i] = *(const bvec8*)&S[(128 + wn + 16 * i + l) * 32 + rpos];
    }
#pragma unroll
    for (int i = 0; i < 4; i++)
#pragma unroll
      for (int j = 0; j < 4; j++)
        acc[i][j] = MFMA16(af[i], bf[j], acc[i][j]);
    __syncthreads();
  }
#pragma unroll
  for (int mi = 0; mi < 4; mi++)
#pragma unroll
    for (int ni = 0; ni < 4; ni++) {
      int row = m0 + wm + mi * 16 + q * 4;
      int col = n0 + wn + ni * 16 + l;
      if (isQ) {
        float bvv = bq[col];
#pragma unroll
        for (int r = 0; r < 4; r++)
          Qb[(size_t)(row + r) * 1024 + col] = f2b((acc[mi][ni][r] + bvv) * 0.125f);
      } else if (col < 1024) {
        float bvv = bk[col];
#pragma unroll
        for (int r = 0; r < 4; r++)
          Kb[(size_t)(row + r) * 1024 + col] = f2b(acc[mi][ni][r] + bvv);
      } else {
        int vcol = col - 1024;
        float bvv = bv[vcol];
        int b = row >> 11, s = row & 2047;
        int h = vcol >> 6, d = vcol & 63;
        ushort4 o;
        o.x = f2b(acc[mi][ni][0] + bvv);
        o.y = f2b(acc[mi][ni][1] + bvv);
        o.z = f2b(acc[mi][ni][2] + bvv);
        o.w = f2b(acc[mi][ni][3] + bvv);
        *(ushort4*)&Vtb[((size_t)(b * 16 + h) * 64 + d) * 2048 + s] = o;
      }
    }
}

// ---------------- templated MFMA GEMM: C[M][N] = A[M][K] @ BT[N][K]^T --------
// Tile TM x TN (2x2 wave grid), BK=32, global_load_lds w=16, rotate-swizzle.
// Split-K via gridDim.z. flags: 1=relu, 2=bf16 outB, 4=fp32 outF, 8=add resid,
// 16=raw split-K partial (acc -> outF + z*M*N).
template <int TM, int TN>
__global__ __launch_bounds__(256, TM == 64 ? 4 : 3) void k_gemm(
    const u16* __restrict__ A, const u16* __restrict__ BT,
    const float* __restrict__ bias, const float* __restrict__ resid,
    float* __restrict__ outF, u16* __restrict__ outB,
    int M, int N, int Kstride, int Klen, float scale, int flags) {
  constexpr int WM = TM / 2, WN = TN / 2;
  constexpr int MI = WM / 16, NI = WN / 16;
  constexpr int NCALL = (TM + TN) / 64;  // 16-row staging calls per wave
  __shared__ u16 S[(TM + TN) * 32];      // A rows [0,TM), B rows [TM,TM+TN)
  const int tid = threadIdx.x, w = tid >> 6, lane = tid & 63;
  const int q = lane >> 4, l = lane & 15;
  const int m0 = blockIdx.y * TM, n0 = blockIdx.x * TN;
  const int kbeg = blockIdx.z * Klen;
  const int wm = (w >> 1) * WM, wn = (w & 1) * WN;
  const int srow = lane >> 2, sgrp = lane & 3;
  const int gcol = ((sgrp + (srow >> 1)) & 3) * 8;
  const int rpos = ((q + 4 - ((l >> 1) & 3)) & 3) * 8;
  const u16* gp[NCALL];
  u16* lp[NCALL];
#pragma unroll
  for (int c = 0; c < NCALL; c++) {
    int r0 = (w * NCALL + c) * 16;
    gp[c] = (r0 < TM) ? A + (size_t)(m0 + r0 + srow) * Kstride + kbeg + gcol
                      : BT + (size_t)(n0 + r0 - TM + srow) * Kstride + kbeg + gcol;
    lp[c] = &S[r0 * 32];
  }
  fvec4 acc[MI][NI] = {};
#pragma unroll 1
  for (int k0 = 0; k0 < Klen; k0 += 32) {
#pragma unroll
    for (int c = 0; c < NCALL; c++) gl_lds16(gp[c] + k0, lp[c]);
    __syncthreads();
    bvec8 af[MI], bf[NI];
#pragma unroll
    for (int i = 0; i < MI; i++)
      af[i] = *(const bvec8*)&S[(wm + 16 * i + l) * 32 + rpos];
#pragma unroll
    for (int j = 0; j < NI; j++)
      bf[j] = *(const bvec8*)&S[(TM + wn + 16 * j + l) * 32 + rpos];
#pragma unroll
    for (int i = 0; i < MI; i++)
#pragma unroll
      for (int j = 0; j < NI; j++)
        acc[i][j] = MFMA16(af[i], bf[j], acc[i][j]);
    __syncthreads();
  }
  if (flags & 16) {  // raw split-K partial
    float* po = outF + (size_t)blockIdx.z * M * N;
#pragma unroll
    for (int mi = 0; mi < MI; mi++)
#pragma unroll
      for (int ni = 0; ni < NI; ni++) {
        int row = m0 + wm + mi * 16 + q * 4;
        int col = n0 + wn + ni * 16 + l;
#pragma unroll
        for (int r = 0; r < 4; r++)
          po[(size_t)(row + r) * N + col] = acc[mi][ni][r];
      }
    return;
  }
#pragma unroll
  for (int mi = 0; mi < MI; mi++)
#pragma unroll
    for (int ni = 0; ni < NI; ni++) {
      int row = m0 + wm + mi * 16 + q * 4;
      int col = n0 + wn + ni * 16 + l;
      float bvv = bias[col];
#pragma unroll
      for (int r = 0; r < 4; r++) {
        float v = (acc[mi][ni][r] + bvv) * scale;
        if (flags & 1) v = fmaxf(v, 0.0f);
        size_t idx = (size_t)(row + r) * N + col;
        if (flags & 8) v += resid[idx];
        if (flags & 2) outB[idx] = f2b(v);
        if (flags & 4) outF[idx] = v;
      }
    }
}

// ---------------- block-cooperative no-max flash attention, s-split ----------
// grid (512, 2): x = 32 bh * 16 t-blocks, y = s-split (1024 s each; exact since
// no-max softmax is linear in s). Emits unnormalized fp32 o-partials + l-sums.
__global__ __launch_bounds__(256, 4) void k_attn(
    const u16* __restrict__ Q, const u16* __restrict__ Kb,
    const u16* __restrict__ Vt, float* __restrict__ opart,
    float* __restrict__ lpart) {
  __shared__ u16 Ks[64 * 64];        // [s][d], col groups rotated by s&7
  __shared__ u16 Vs[64 * 64];        // [d][s], col groups rotated by d&7
  __shared__ u16 Ps[4][2][16 * 72];  // per-wave P, stride 72 (16B-aligned, 2-way)
  const int tid = threadIdx.x, w = tid >> 6, lane = tid & 63;
  const int q = lane >> 4, l = lane & 15;
  const int blk = blockIdx.x;
  const int bh = blk >> 4, tb = blk & 15;
  const int b = bh >> 4, h = bh & 15;
  const int t0 = tb * 128 + w * 32;
  const int sbeg = blockIdx.y * 1024;
  float* op = opart + (size_t)blockIdx.y * 4096 * 1024;
  float* lp = lpart + (size_t)blockIdx.y * 4096 * 16;
  const u16* Qp = Q + (size_t)(b * 2048 + t0) * 1024 + h * 64;
  const u16* Kp = Kb + (size_t)(b * 2048) * 1024 + h * 64;
  const u16* Vp = Vt + (size_t)bh * 64 * 2048;
  const int rowin = lane >> 3, grp = lane & 7;
  const int gcol = ((grp + rowin) & 7) * 8;
  const int kc0 = ((q + 8 - (l & 7)) & 7) * 8;       // k-group q
  const int kc1 = ((q + 12 - (l & 7)) & 7) * 8;      // k-group q+4
  bvec8 aQ[2][2];
#pragma unroll
  for (int ti = 0; ti < 2; ti++)
#pragma unroll
    for (int kh = 0; kh < 2; kh++)
      aQ[ti][kh] = *(const bvec8*)&Qp[(size_t)(ti * 16 + l) * 1024 + kh * 32 + q * 8];
  fvec4 o[2][4] = {};
  float ls[2][4] = {};
#pragma unroll 1
  for (int s0 = sbeg; s0 < sbeg + 1024; s0 += 64) {
    gl_lds16(Kp + (size_t)(s0 + w * 8 + rowin) * 1024 + gcol, &Ks[(w * 8) * 64]);
    gl_lds16(Kp + (size_t)(s0 + 32 + w * 8 + rowin) * 1024 + gcol, &Ks[(32 + w * 8) * 64]);
    gl_lds16(Vp + (size_t)(w * 8 + rowin) * 2048 + s0 + gcol, &Vs[(w * 8) * 64]);
    gl_lds16(Vp + (size_t)(32 + w * 8 + rowin) * 2048 + s0 + gcol, &Vs[(32 + w * 8) * 64]);
    __syncthreads();  // compiler drains vmcnt before barrier -> staged data visible
    fvec4 sc[2][4];
#pragma unroll
    for (int ti = 0; ti < 2; ti++)
#pragma unroll
      for (int ss = 0; ss < 4; ss++) sc[ti][ss] = (fvec4){0.f, 0.f, 0.f, 0.f};
#pragma unroll
    for (int ss = 0; ss < 4; ss++) {
      const int ro = (ss * 16 + l) * 64;
      bvec8 kf0 = *(const bvec8*)&Ks[ro + kc0];
      bvec8 kf1 = *(const bvec8*)&Ks[ro + kc1];
#pragma unroll
      for (int ti = 0; ti < 2; ti++) {
        sc[ti][ss] = MFMA16(aQ[ti][0], kf0, sc[ti][ss]);
        sc[ti][ss] = MFMA16(aQ[ti][1], kf1, sc[ti][ss]);
      }
    }
#pragma unroll
    for (int ti = 0; ti < 2; ti++)
#pragma unroll
      for (int ss = 0; ss < 4; ss++)
#pragma unroll
        for (int r = 0; r < 4; r++) {
          float p = __expf(sc[ti][ss][r]);
          ls[ti][r] += p;
          Ps[w][ti][(q * 4 + r) * 72 + ss * 16 + l] = f2b_t(p);
        }
    asm volatile("s_waitcnt lgkmcnt(0)" ::: "memory");  // P writes -> same-wave reads
    bvec8 bV[4][2];
#pragma unroll
    for (int dt = 0; dt < 4; dt++) {
      const int ro = (dt * 16 + l) * 64;
      bV[dt][0] = *(const bvec8*)&Vs[ro + kc0];
      bV[dt][1] = *(const bvec8*)&Vs[ro + kc1];
    }
#pragma unroll
    for (int ti = 0; ti < 2; ti++) {
      bvec8 aP0 = *(const bvec8*)&Ps[w][ti][l * 72 + q * 8];
      bvec8 aP1 = *(const bvec8*)&Ps[w][ti][l * 72 + 32 + q * 8];
#pragma unroll
      for (int dt = 0; dt < 4; dt++) {
        o[ti][dt] = MFMA16(aP0, bV[dt][0], o[ti][dt]);
        o[ti][dt] = MFMA16(aP1, bV[dt][1], o[ti][dt]);
      }
    }
    __syncthreads();  // all waves done reading Ks/Vs before next stage
  }
#pragma unroll
  for (int ti = 0; ti < 2; ti++)
#pragma unroll
    for (int r = 0; r < 4; r++) {
      float s = ls[ti][r];
      s += __shfl_xor(s, 1, 64);
      s += __shfl_xor(s, 2, 64);
      s += __shfl_xor(s, 4, 64);
      s += __shfl_xor(s, 8, 64);  // sum over the 16 lanes of quad q (rows q*4+r)
      int trow = b * 2048 + t0 + ti * 16 + q * 4 + r;
      if (l == 0) lp[trow * 16 + h] = s;
#pragma unroll
      for (int dt = 0; dt < 4; dt++)
        op[(size_t)trow * 1024 + h * 64 + dt * 16 + l] = o[ti][dt][r];
    }
}

// ---------------- attention combine: ctx = (o0+o1) / (l0+l1) ----------------
__global__ __launch_bounds__(256) void k_actx(const float* __restrict__ opart,
                                              const float* __restrict__ lpart,
                                              u16* __restrict__ ctx) {
  int row = blockIdx.x, c0 = threadIdx.x * 4;
  int h = c0 >> 6;
  float lsum = lpart[row * 16 + h] + lpart[4096 * 16 + row * 16 + h];
  float inv = 1.0f / lsum;
  float4 a = *(const float4*)&opart[(size_t)row * 1024 + c0];
  float4 b = *(const float4*)&opart[(size_t)4096 * 1024 + (size_t)row * 1024 + c0];
  ushort4 o;
  o.x = f2b((a.x + b.x) * inv);
  o.y = f2b((a.y + b.y) * inv);
  o.z = f2b((a.z + b.z) * inv);
  o.w = f2b((a.w + b.w) * inv);
  *(ushort4*)&ctx[(size_t)row * 1024 + c0] = o;
}

// ---- LayerNorm over dim 1024, fused split-K combine: y = Σparts+bias+res ----
__global__ __launch_bounds__(256) void k_lnp(
    const float* __restrict__ parts, int nparts,
    const float* __restrict__ bias, const float* __restrict__ resid,
    const float* __restrict__ g, const float* __restrict__ be,
    float* __restrict__ xf, u16* __restrict__ xb) {
  __shared__ float sm[8];
  int row = blockIdx.x, tid = threadIdx.x;
  size_t base = (size_t)row * 1024;
  const size_t pstride = (size_t)4096 * 1024;
  float v[4], s = 0.f, ss = 0.f;
#pragma unroll
  for (int j = 0; j < 4; j++) {
    int c = tid + j * 256;
    float acc = bias[c] + resid[base + c];
    for (int z = 0; z < nparts; z++) acc += parts[z * pstride + base + c];
    v[j] = acc;
    s += acc; ss += acc * acc;
  }
#pragma unroll
  for (int off = 32; off; off >>= 1) {
    s += __shfl_down(s, off, 64);
    ss += __shfl_down(ss, off, 64);
  }
  int w = tid >> 6;
  if ((tid & 63) == 0) { sm[w] = s; sm[4 + w] = ss; }
  __syncthreads();
  float S = sm[0] + sm[1] + sm[2] + sm[3];
  float SS = sm[4] + sm[5] + sm[6] + sm[7];
  float mean = S * (1.0f / 1024.0f);
  float var = SS * (1.0f / 1024.0f) - mean * mean;
  float rstd = rsqrtf(var + 1e-5f);
#pragma unroll
  for (int j = 0; j < 4; j++) {
    int c = tid + j * 256;
    float o = (v[j] - mean) * rstd * g[c] + be[c];
    xf[base + c] = o;
    if (xb) xb[base + c] = f2b(o);
  }
}

extern "C" void kernel_launch(void* const* d_in, const int* in_sizes, int n_in,
                              void* d_out, int out_size, void* d_ws, size_t ws_size,
                              hipStream_t stream) {
  (void)in_sizes; (void)n_in; (void)out_size; (void)ws_size;
  const float* tgt = (const float*)d_in[0];
  const float* mem = (const float*)d_in[1];
  const float* wq  = (const float*)d_in[2];
  const float* bq  = (const float*)d_in[3];
  const float* wk  = (const float*)d_in[4];
  const float* bk  = (const float*)d_in[5];
  const float* wv  = (const float*)d_in[6];
  const float* bv  = (const float*)d_in[7];
  const float* wo  = (const float*)d_in[8];
  const float* bo  = (const float*)d_in[9];
  const float* w1  = (const float*)d_in[10];
  const float* b1  = (const float*)d_in[11];
  const float* w2  = (const float*)d_in[12];
  const float* b2  = (const float*)d_in[13];
  const float* g1  = (const float*)d_in[14];
  const float* be1 = (const float*)d_in[15];
  const float* g2  = (const float*)d_in[16];
  const float* be2 = (const float*)d_in[17];
  float* out = (float*)d_out;

  char* ws = (char*)d_ws;
  size_t off = 0;
  auto take = [&](size_t bytes) { char* p = ws + off; off += bytes; return p; };
  const size_t MB = 1024 * 1024;
  u16* tgt_b = (u16*)take(8 * MB);    // [4096][1024] bf16
  u16* mem_b = (u16*)take(8 * MB);
  u16* wqT   = (u16*)take(2 * MB);    // [1024][1024]
  u16* wkvT  = (u16*)take(4 * MB);    // [2048][1024]: wk^T then wv^T
  u16* woT   = (u16*)take(2 * MB);
  u16* w1T   = (u16*)take(8 * MB);    // [4096][1024]
  u16* w2T   = (u16*)take(8 * MB);    // [1024][4096]
  u16* Qb    = (u16*)take(8 * MB);
  u16* Kb    = (u16*)take(8 * MB);
  u16* Vtb   = (u16*)take(8 * MB);    // [32][64][2048]
  u16* ctx   = (u16*)take(8 * MB);
  float* opart = (float*)take(32 * MB);  // attn o-partials [2][4096][1024] fp32
  float* opj   = (float*)take(32 * MB);  // O-proj split-K partials [2][4096][1024]
  float* lpart = (float*)take(1 * MB);   // attn l-sums [2][4096][16] fp32
  float* xf  = (float*)take(16 * MB);
  u16* xb    = (u16*)take(8 * MB);
  u16* hbuf  = Qb;                    // [4096][4096] bf16 over Qb..ctx (dead after O-proj)
  float* fp2 = opart;                 // FFN2 partials [2][4096][1024] (opart dead)

  // 1. converts + weight transposes (one launch)
  k_pre<<<20480, 256, 0, stream>>>(tgt, mem, wq, wk, wv, wo, w1, w2,
                                   tgt_b, mem_b, wqT, wkvT, woT, w1T, w2T);
  // 2. Q + KV projections (one launch, 768 blocks, V-transpose fused)
  k_qkv<<<768, 256, 0, stream>>>(tgt_b, mem_b, wqT, wkvT, bq, bk, bv,
                                 Qb, Kb, Vtb);
  // 3. attention, s-split=2 -> 1024 blocks, 4 blk/CU
  k_attn<<<dim3(512, 2), 256, 0, stream>>>(Qb, Kb, Vtb, opart, lpart);
  k_actx<<<4096, 256, 0, stream>>>(opart, lpart, ctx);
  // 4. O-proj split-K=2 raw partials -> opj (r4 config)
  k_gemm<64, 128><<<dim3(8, 64, 2), 256, 0, stream>>>(
      ctx, woT, nullptr, nullptr, opj, nullptr,
      4096, 1024, 1024, 512, 1.0f, 16);
  // 5. LN1 fused combine: y = opj0+opj1+bo+tgt
  k_lnp<<<4096, 256, 0, stream>>>(opj, 2, bo, tgt, g1, be1, xf, xb);
  // 6. FFN1: relu(x @ w1 + b1), 128x128, 1024 blocks (r4 config)
  k_gemm<128, 128><<<dim3(32, 32), 256, 0, stream>>>(
      xb, w1T, b1, nullptr, nullptr, hbuf,
      4096, 4096, 1024, 1024, 1.0f, 1 | 2);
  // 7. FFN2 split-K=2 raw partials -> fp2 (r4 config: 66us, best measured)
  k_gemm<64, 128><<<dim3(8, 64, 2), 256, 0, stream>>>(
      hbuf, w2T, nullptr, nullptr, fp2, nullptr,
      4096, 1024, 4096, 2048, 1.0f, 16);
  // 8. LN2 fused combine: y = fp2_0+fp2_1+b2+xf
  k_lnp<<<4096, 256, 0, stream>>>(fp2, 2, b2, xf, g2, be2, out, nullptr);
}

// Round 8
// 394.048 us; speedup vs baseline: 1.1343x; 1.0247x over previous
//
#include <hip/hip_runtime.h>

// Round 8: BK=64 K-loop in all GEMMs (halves barrier-drain count; attention's
// proven 64-col &7-rotation swizzle), O-proj split-K dropped (traffic > occupancy
// at 16 iters), 128^2 path at 4 blocks/CU.

typedef unsigned short u16;
typedef __attribute__((ext_vector_type(8))) short bvec8;   // 8 bf16 (4 VGPRs)
typedef __attribute__((ext_vector_type(4))) float fvec4;

#define MFMA16(a, b, c) __builtin_amdgcn_mfma_f32_16x16x32_bf16((a), (b), (c), 0, 0, 0)

__device__ __forceinline__ u16 f2b(float f) {
  union { float f; unsigned u; } x; x.f = f;
  unsigned u = x.u;
  return (u16)((u + 0x7FFFu + ((u >> 16) & 1u)) >> 16);  // RNE
}
__device__ __forceinline__ u16 f2b_t(float f) {  // truncate (cheap, for P only)
  union { float f; unsigned u; } x; x.f = f;
  return (u16)(x.u >> 16);
}
// async global->LDS, 16B/lane; LDS dest = wave-uniform base + lane*16
__device__ __forceinline__ void gl_lds16(const u16* g, u16* lds) {
  __builtin_amdgcn_global_load_lds(
      (const __attribute__((address_space(1))) void*)g,
      (__attribute__((address_space(3))) void*)lds, 16, 0, 0);
}

// ------- merged prep: fp32->bf16 converts (blocks 0..8191) + all weight
// ------- transposes W[K][N] -> WT[N][K] bf16 (blocks 8192..20479) ----------
__global__ __launch_bounds__(256) void k_pre(
    const float* __restrict__ tgt, const float* __restrict__ mem,
    const float* __restrict__ wq, const float* __restrict__ wk,
    const float* __restrict__ wv, const float* __restrict__ wo,
    const float* __restrict__ w1, const float* __restrict__ w2,
    u16* __restrict__ tgt_b, u16* __restrict__ mem_b,
    u16* __restrict__ wqT, u16* __restrict__ wkvT, u16* __restrict__ woT,
    u16* __restrict__ w1T, u16* __restrict__ w2T) {
  __shared__ float t[32][33];
  int bb = blockIdx.x;
  if (bb < 8192) {  // activation converts
    const float* in = (bb < 4096) ? tgt : mem;
    u16* outp = (bb < 4096) ? tgt_b : mem_b;
    int i = (bb & 4095) * 256 + threadIdx.x;
    float4 v = ((const float4*)in)[i];
    ushort4 o;
    o.x = f2b(v.x); o.y = f2b(v.y); o.z = f2b(v.z); o.w = f2b(v.w);
    ((ushort4*)outp)[i] = o;
    return;
  }
  int b = bb - 8192;
  const float* W; u16* WT; int K, N, bx, by;
  if (b < 4096) {            // wq/wk/wv/wo: 1024x1024, 1024 tiles each
    int m = b >> 10, tt = b & 1023;
    bx = tt & 31; by = tt >> 5; K = 1024; N = 1024;
    W = (m == 0) ? wq : (m == 1) ? wk : (m == 2) ? wv : wo;
    WT = (m == 0) ? wqT : (m == 1) ? wkvT : (m == 2) ? wkvT + 1024 * 1024 : woT;
  } else if (b < 8192) {     // w1: K=1024, N=4096
    int tt = b - 4096; bx = tt & 127; by = tt >> 7; K = 1024; N = 4096;
    W = w1; WT = w1T;
  } else {                   // w2: K=4096, N=1024
    int tt = b - 8192; bx = tt & 31; by = tt >> 5; K = 4096; N = 1024;
    W = w2; WT = w2T;
  }
  int tx = threadIdx.x & 31, ty = threadIdx.x >> 5;
  int n0 = bx * 32, k0 = by * 32;
#pragma unroll
  for (int i = 0; i < 4; i++)
    t[ty + i * 8][tx] = W[(size_t)(k0 + ty + i * 8) * N + n0 + tx];
  __syncthreads();
#pragma unroll
  for (int i = 0; i < 4; i++)
    WT[(size_t)(n0 + ty + i * 8) * K + k0 + tx] = f2b(t[tx][ty + i * 8]);
}

// ------- merged Q-proj + KV-proj, 128x128 tiles, BK=64, V-transpose fused ----
// blocks 0..255: Q = (tgt_b @ wqT^T + bq)*0.125 -> Qb bf16
// blocks 256..767: KV = mem_b @ wkvT^T; col<1024 -> Kb (+bk); col>=1024 ->
//   Vt[bh][d][s] (+bv) via packed 8B stores (4 r-values = 4 consecutive s).
__global__ __launch_bounds__(256, 4) void k_qkv(
    const u16* __restrict__ tgt_b, const u16* __restrict__ mem_b,
    const u16* __restrict__ wqT, const u16* __restrict__ wkvT,
    const float* __restrict__ bq, const float* __restrict__ bk,
    const float* __restrict__ bv,
    u16* __restrict__ Qb, u16* __restrict__ Kb, u16* __restrict__ Vtb) {
  __shared__ u16 S[256 * 64];
  const int tid = threadIdx.x, w = tid >> 6, lane = tid & 63;
  const int q = lane >> 4, l = lane & 15;
  const bool isQ = blockIdx.x < 256;
  const int id = isQ ? blockIdx.x : blockIdx.x - 256;
  const int nx = isQ ? 8 : 16;
  const int m0 = (id / nx) * 128, n0 = (id % nx) * 128;
  const u16* A = isQ ? tgt_b : mem_b;
  const u16* BT = isQ ? wqT : wkvT;
  const int wm = (w >> 1) * 64, wn = (w & 1) * 64;
  // BK=64 staging: 1KB/call = 8 rows x 128B; lane i -> row i>>3, group i&7,
  // global col group rotated by row&7 (LDS linear, global permuted).
  const int rowin = lane >> 3, grp = lane & 7;
  const int gcol = ((grp + rowin) & 7) * 8;
  // frag read: row&7 == l&7; LDS slot holding global k-group G: (G+8-(l&7))&7
  const int kc0 = ((q + 8 - (l & 7)) & 7) * 8;       // k-half 0, group q
  const int kc1 = ((q + 12 - (l & 7)) & 7) * 8;      // k-half 1, group q+4
  const u16* gp[8];
  u16* lp[8];
#pragma unroll
  for (int c = 0; c < 8; c++) {
    int r0 = (w * 8 + c) * 8;
    gp[c] = (r0 < 128) ? A + (size_t)(m0 + r0 + rowin) * 1024 + gcol
                       : BT + (size_t)(n0 + r0 - 128 + rowin) * 1024 + gcol;
    lp[c] = &S[r0 * 64];
  }
  fvec4 acc[4][4] = {};
#pragma unroll 1
  for (int k0 = 0; k0 < 1024; k0 += 64) {
#pragma unroll
    for (int c = 0; c < 8; c++) gl_lds16(gp[c] + k0, lp[c]);
    __syncthreads();
#pragma unroll
    for (int kh = 0; kh < 2; kh++) {
      const int kc = kh ? kc1 : kc0;
      bvec8 af[4], bf[4];
#pragma unroll
      for (int i = 0; i < 4; i++) {
        af[i] = *(const bvec8*)&S[(wm + 16 * i + l) * 64 + kc];
        bf[i] = *(const bvec8*)&S[(128 + wn + 16 * i + l) * 64 + kc];
      }
#pragma unroll
      for (int i = 0; i < 4; i++)
#pragma unroll
        for (int j = 0; j < 4; j++)
          acc[i][j] = MFMA16(af[i], bf[j], acc[i][j]);
    }
    __syncthreads();
  }
#pragma unroll
  for (int mi = 0; mi < 4; mi++)
#pragma unroll
    for (int ni = 0; ni < 4; ni++) {
      int row = m0 + wm + mi * 16 + q * 4;
      int col = n0 + wn + ni * 16 + l;
      if (isQ) {
        float bvv = bq[col];
#pragma unroll
        for (int r = 0; r < 4; r++)
          Qb[(size_t)(row + r) * 1024 + col] = f2b((acc[mi][ni][r] + bvv) * 0.125f);
      } else if (col < 1024) {
        float bvv = bk[col];
#pragma unroll
        for (int r = 0; r < 4; r++)
          Kb[(size_t)(row + r) * 1024 + col] = f2b(acc[mi][ni][r] + bvv);
      } else {
        int vcol = col - 1024;
        float bvv = bv[vcol];
        int b = row >> 11, s = row & 2047;
        int h = vcol >> 6, d = vcol & 63;
        ushort4 o;
        o.x = f2b(acc[mi][ni][0] + bvv);
        o.y = f2b(acc[mi][ni][1] + bvv);
        o.z = f2b(acc[mi][ni][2] + bvv);
        o.w = f2b(acc[mi][ni][3] + bvv);
        *(ushort4*)&Vtb[((size_t)(b * 16 + h) * 64 + d) * 2048 + s] = o;
      }
    }
}

// ---------------- templated MFMA GEMM: C[M][N] = A[M][K] @ BT[N][K]^T --------
// Tile TM x TN (2x2 wave grid), BK=64 (halved barrier count vs BK=32),
// global_load_lds w=16, &7-rotation swizzle. Split-K via gridDim.z.
// flags: 1=relu, 2=bf16 outB, 4=fp32 outF, 8=add resid, 16=raw split-K partial.
template <int TM, int TN>
__global__ __launch_bounds__(256, 4) void k_gemm(
    const u16* __restrict__ A, const u16* __restrict__ BT,
    const float* __restrict__ bias, const float* __restrict__ resid,
    float* __restrict__ outF, u16* __restrict__ outB,
    int M, int N, int Kstride, int Klen, float scale, int flags) {
  constexpr int WM = TM / 2, WN = TN / 2;
  constexpr int MI = WM / 16, NI = WN / 16;
  constexpr int NCALL = (TM + TN) / 32;  // 8-row staging calls per wave
  __shared__ u16 S[(TM + TN) * 64];      // A rows [0,TM), B rows [TM,TM+TN)
  const int tid = threadIdx.x, w = tid >> 6, lane = tid & 63;
  const int q = lane >> 4, l = lane & 15;
  const int m0 = blockIdx.y * TM, n0 = blockIdx.x * TN;
  const int kbeg = blockIdx.z * Klen;
  const int wm = (w >> 1) * WM, wn = (w & 1) * WN;
  const int rowin = lane >> 3, grp = lane & 7;
  const int gcol = ((grp + rowin) & 7) * 8;
  const int kc0 = ((q + 8 - (l & 7)) & 7) * 8;
  const int kc1 = ((q + 12 - (l & 7)) & 7) * 8;
  const u16* gp[NCALL];
  u16* lp[NCALL];
#pragma unroll
  for (int c = 0; c < NCALL; c++) {
    int r0 = (w * NCALL + c) * 8;
    gp[c] = (r0 < TM) ? A + (size_t)(m0 + r0 + rowin) * Kstride + kbeg + gcol
                      : BT + (size_t)(n0 + r0 - TM + rowin) * Kstride + kbeg + gcol;
    lp[c] = &S[r0 * 64];
  }
  fvec4 acc[MI][NI] = {};
#pragma unroll 1
  for (int k0 = 0; k0 < Klen; k0 += 64) {
#pragma unroll
    for (int c = 0; c < NCALL; c++) gl_lds16(gp[c] + k0, lp[c]);
    __syncthreads();
#pragma unroll
    for (int kh = 0; kh < 2; kh++) {
      const int kc = kh ? kc1 : kc0;
      bvec8 af[MI], bf[NI];
#pragma unroll
      for (int i = 0; i < MI; i++)
        af[i] = *(const bvec8*)&S[(wm + 16 * i + l) * 64 + kc];
#pragma unroll
      for (int j = 0; j < NI; j++)
        bf[j] = *(const bvec8*)&S[(TM + wn + 16 * j + l) * 64 + kc];
#pragma unroll
      for (int i = 0; i < MI; i++)
#pragma unroll
        for (int j = 0; j < NI; j++)
          acc[i][j] = MFMA16(af[i], bf[j], acc[i][j]);
    }
    __syncthreads();
  }
  if (flags & 16) {  // raw split-K partial
    float* po = outF + (size_t)blockIdx.z * M * N;
#pragma unroll
    for (int mi = 0; mi < MI; mi++)
#pragma unroll
      for (int ni = 0; ni < NI; ni++) {
        int row = m0 + wm + mi * 16 + q * 4;
        int col = n0 + wn + ni * 16 + l;
#pragma unroll
        for (int r = 0; r < 4; r++)
          po[(size_t)(row + r) * N + col] = acc[mi][ni][r];
      }
    return;
  }
#pragma unroll
  for (int mi = 0; mi < MI; mi++)
#pragma unroll
    for (int ni = 0; ni < NI; ni++) {
      int row = m0 + wm + mi * 16 + q * 4;
      int col = n0 + wn + ni * 16 + l;
      float bvv = bias[col];
#pragma unroll
      for (int r = 0; r < 4; r++) {
        float v = (acc[mi][ni][r] + bvv) * scale;
        if (flags & 1) v = fmaxf(v, 0.0f);
        size_t idx = (size_t)(row + r) * N + col;
        if (flags & 8) v += resid[idx];
        if (flags & 2) outB[idx] = f2b(v);
        if (flags & 4) outF[idx] = v;
      }
    }
}

// ---------------- block-cooperative no-max flash attention, s-split ----------
// grid (512, 2): x = 32 bh * 16 t-blocks, y = s-split (1024 s each; exact since
// no-max softmax is linear in s). Emits unnormalized fp32 o-partials + l-sums.
__global__ __launch_bounds__(256, 4) void k_attn(
    const u16* __restrict__ Q, const u16* __restrict__ Kb,
    const u16* __restrict__ Vt, float* __restrict__ opart,
    float* __restrict__ lpart) {
  __shared__ u16 Ks[64 * 64];        // [s][d], col groups rotated by s&7
  __shared__ u16 Vs[64 * 64];        // [d][s], col groups rotated by d&7
  __shared__ u16 Ps[4][2][16 * 72];  // per-wave P, stride 72 (16B-aligned, 2-way)
  const int tid = threadIdx.x, w = tid >> 6, lane = tid & 63;
  const int q = lane >> 4, l = lane & 15;
  const int blk = blockIdx.x;
  const int bh = blk >> 4, tb = blk & 15;
  const int b = bh >> 4, h = bh & 15;
  const int t0 = tb * 128 + w * 32;
  const int sbeg = blockIdx.y * 1024;
  float* op = opart + (size_t)blockIdx.y * 4096 * 1024;
  float* lp = lpart + (size_t)blockIdx.y * 4096 * 16;
  const u16* Qp = Q + (size_t)(b * 2048 + t0) * 1024 + h * 64;
  const u16* Kp = Kb + (size_t)(b * 2048) * 1024 + h * 64;
  const u16* Vp = Vt + (size_t)bh * 64 * 2048;
  const int rowin = lane >> 3, grp = lane & 7;
  const int gcol = ((grp + rowin) & 7) * 8;
  const int kc0 = ((q + 8 - (l & 7)) & 7) * 8;       // k-group q
  const int kc1 = ((q + 12 - (l & 7)) & 7) * 8;      // k-group q+4
  bvec8 aQ[2][2];
#pragma unroll
  for (int ti = 0; ti < 2; ti++)
#pragma unroll
    for (int kh = 0; kh < 2; kh++)
      aQ[ti][kh] = *(const bvec8*)&Qp[(size_t)(ti * 16 + l) * 1024 + kh * 32 + q * 8];
  fvec4 o[2][4] = {};
  float ls[2][4] = {};
#pragma unroll 1
  for (int s0 = sbeg; s0 < sbeg + 1024; s0 += 64) {
    gl_lds16(Kp + (size_t)(s0 + w * 8 + rowin) * 1024 + gcol, &Ks[(w * 8) * 64]);
    gl_lds16(Kp + (size_t)(s0 + 32 + w * 8 + rowin) * 1024 + gcol, &Ks[(32 + w * 8) * 64]);
    gl_lds16(Vp + (size_t)(w * 8 + rowin) * 2048 + s0 + gcol, &Vs[(w * 8) * 64]);
    gl_lds16(Vp + (size_t)(32 + w * 8 + rowin) * 2048 + s0 + gcol, &Vs[(32 + w * 8) * 64]);
    __syncthreads();  // compiler drains vmcnt before barrier -> staged data visible
    fvec4 sc[2][4];
#pragma unroll
    for (int ti = 0; ti < 2; ti++)
#pragma unroll
      for (int ss = 0; ss < 4; ss++) sc[ti][ss] = (fvec4){0.f, 0.f, 0.f, 0.f};
#pragma unroll
    for (int ss = 0; ss < 4; ss++) {
      const int ro = (ss * 16 + l) * 64;
      bvec8 kf0 = *(const bvec8*)&Ks[ro + kc0];
      bvec8 kf1 = *(const bvec8*)&Ks[ro + kc1];
#pragma unroll
      for (int ti = 0; ti < 2; ti++) {
        sc[ti][ss] = MFMA16(aQ[ti][0], kf0, sc[ti][ss]);
        sc[ti][ss] = MFMA16(aQ[ti][1], kf1, sc[ti][ss]);
      }
    }
#pragma unroll
    for (int ti = 0; ti < 2; ti++)
#pragma unroll
      for (int ss = 0; ss < 4; ss++)
#pragma unroll
        for (int r = 0; r < 4; r++) {
          float p = __expf(sc[ti][ss][r]);
          ls[ti][r] += p;
          Ps[w][ti][(q * 4 + r) * 72 + ss * 16 + l] = f2b_t(p);
        }
    asm volatile("s_waitcnt lgkmcnt(0)" ::: "memory");  // P writes -> same-wave reads
    bvec8 bV[4][2];
#pragma unroll
    for (int dt = 0; dt < 4; dt++) {
      const int ro = (dt * 16 + l) * 64;
      bV[dt][0] = *(const bvec8*)&Vs[ro + kc0];
      bV[dt][1] = *(const bvec8*)&Vs[ro + kc1];
    }
#pragma unroll
    for (int ti = 0; ti < 2; ti++) {
      bvec8 aP0 = *(const bvec8*)&Ps[w][ti][l * 72 + q * 8];
      bvec8 aP1 = *(const bvec8*)&Ps[w][ti][l * 72 + 32 + q * 8];
#pragma unroll
      for (int dt = 0; dt < 4; dt++) {
        o[ti][dt] = MFMA16(aP0, bV[dt][0], o[ti][dt]);
        o[ti][dt] = MFMA16(aP1, bV[dt][1], o[ti][dt]);
      }
    }
    __syncthreads();  // all waves done reading Ks/Vs before next stage
  }
#pragma unroll
  for (int ti = 0; ti < 2; ti++)
#pragma unroll
    for (int r = 0; r < 4; r++) {
      float s = ls[ti][r];
      s += __shfl_xor(s, 1, 64);
      s += __shfl_xor(s, 2, 64);
      s += __shfl_xor(s, 4, 64);
      s += __shfl_xor(s, 8, 64);  // sum over the 16 lanes of quad q (rows q*4+r)
      int trow = b * 2048 + t0 + ti * 16 + q * 4 + r;
      if (l == 0) lp[trow * 16 + h] = s;
#pragma unroll
      for (int dt = 0; dt < 4; dt++)
        op[(size_t)trow * 1024 + h * 64 + dt * 16 + l] = o[ti][dt][r];
    }
}

// ---------------- attention combine: ctx = (o0+o1) / (l0+l1) ----------------
__global__ __launch_bounds__(256) void k_actx(const float* __restrict__ opart,
                                              const float* __restrict__ lpart,
                                              u16* __restrict__ ctx) {
  int row = blockIdx.x, c0 = threadIdx.x * 4;
  int h = c0 >> 6;
  float lsum = lpart[row * 16 + h] + lpart[4096 * 16 + row * 16 + h];
  float inv = 1.0f / lsum;
  float4 a = *(const float4*)&opart[(size_t)row * 1024 + c0];
  float4 b = *(const float4*)&opart[(size_t)4096 * 1024 + (size_t)row * 1024 + c0];
  ushort4 o;
  o.x = f2b((a.x + b.x) * inv);
  o.y = f2b((a.y + b.y) * inv);
  o.z = f2b((a.z + b.z) * inv);
  o.w = f2b((a.w + b.w) * inv);
  *(ushort4*)&ctx[(size_t)row * 1024 + c0] = o;
}

// ---- LayerNorm over dim 1024, fused split-K combine: y = Σparts+bias+res ----
__global__ __launch_bounds__(256) void k_lnp(
    const float* __restrict__ parts, int nparts,
    const float* __restrict__ bias, const float* __restrict__ resid,
    const float* __restrict__ g, const float* __restrict__ be,
    float* __restrict__ xf, u16* __restrict__ xb) {
  __shared__ float sm[8];
  int row = blockIdx.x, tid = threadIdx.x;
  size_t base = (size_t)row * 1024;
  const size_t pstride = (size_t)4096 * 1024;
  float v[4], s = 0.f, ss = 0.f;
#pragma unroll
  for (int j = 0; j < 4; j++) {
    int c = tid + j * 256;
    float acc = bias[c] + resid[base + c];
    for (int z = 0; z < nparts; z++) acc += parts[z * pstride + base + c];
    v[j] = acc;
    s += acc; ss += acc * acc;
  }
#pragma unroll
  for (int off = 32; off; off >>= 1) {
    s += __shfl_down(s, off, 64);
    ss += __shfl_down(ss, off, 64);
  }
  int w = tid >> 6;
  if ((tid & 63) == 0) { sm[w] = s; sm[4 + w] = ss; }
  __syncthreads();
  float S = sm[0] + sm[1] + sm[2] + sm[3];
  float SS = sm[4] + sm[5] + sm[6] + sm[7];
  float mean = S * (1.0f / 1024.0f);
  float var = SS * (1.0f / 1024.0f) - mean * mean;
  float rstd = rsqrtf(var + 1e-5f);
#pragma unroll
  for (int j = 0; j < 4; j++) {
    int c = tid + j * 256;
    float o = (v[j] - mean) * rstd * g[c] + be[c];
    xf[base + c] = o;
    if (xb) xb[base + c] = f2b(o);
  }
}

extern "C" void kernel_launch(void* const* d_in, const int* in_sizes, int n_in,
                              void* d_out, int out_size, void* d_ws, size_t ws_size,
                              hipStream_t stream) {
  (void)in_sizes; (void)n_in; (void)out_size; (void)ws_size;
  const float* tgt = (const float*)d_in[0];
  const float* mem = (const float*)d_in[1];
  const float* wq  = (const float*)d_in[2];
  const float* bq  = (const float*)d_in[3];
  const float* wk  = (const float*)d_in[4];
  const float* bk  = (const float*)d_in[5];
  const float* wv  = (const float*)d_in[6];
  const float* bv  = (const float*)d_in[7];
  const float* wo  = (const float*)d_in[8];
  const float* bo  = (const float*)d_in[9];
  const float* w1  = (const float*)d_in[10];
  const float* b1  = (const float*)d_in[11];
  const float* w2  = (const float*)d_in[12];
  const float* b2  = (const float*)d_in[13];
  const float* g1  = (const float*)d_in[14];
  const float* be1 = (const float*)d_in[15];
  const float* g2  = (const float*)d_in[16];
  const float* be2 = (const float*)d_in[17];
  float* out = (float*)d_out;

  char* ws = (char*)d_ws;
  size_t off = 0;
  auto take = [&](size_t bytes) { char* p = ws + off; off += bytes; return p; };
  const size_t MB = 1024 * 1024;
  u16* tgt_b = (u16*)take(8 * MB);    // [4096][1024] bf16
  u16* mem_b = (u16*)take(8 * MB);
  u16* wqT   = (u16*)take(2 * MB);    // [1024][1024]
  u16* wkvT  = (u16*)take(4 * MB);    // [2048][1024]: wk^T then wv^T
  u16* woT   = (u16*)take(2 * MB);
  u16* w1T   = (u16*)take(8 * MB);    // [4096][1024]
  u16* w2T   = (u16*)take(8 * MB);    // [1024][4096]
  u16* Qb    = (u16*)take(8 * MB);
  u16* Kb    = (u16*)take(8 * MB);
  u16* Vtb   = (u16*)take(8 * MB);    // [32][64][2048]
  u16* ctx   = (u16*)take(8 * MB);
  float* opart = (float*)take(32 * MB);  // attn o-partials [2][4096][1024] fp32
  float* opj   = (float*)take(32 * MB);  // O-proj raw out [4096][1024] (+FFN2 z1)
  float* lpart = (float*)take(1 * MB);   // attn l-sums [2][4096][16] fp32
  float* xf  = (float*)take(16 * MB);
  u16* xb    = (u16*)take(8 * MB);
  u16* hbuf  = Qb;                    // [4096][4096] bf16 over Qb..ctx (dead after O-proj)
  float* fp2 = opart;                 // FFN2 partials [2][4096][1024] (opart dead)

  // 1. converts + weight transposes (one launch)
  k_pre<<<20480, 256, 0, stream>>>(tgt, mem, wq, wk, wv, wo, w1, w2,
                                   tgt_b, mem_b, wqT, wkvT, woT, w1T, w2T);
  // 2. Q + KV projections (one launch, 768 blocks, V-transpose fused)
  k_qkv<<<768, 256, 0, stream>>>(tgt_b, mem_b, wqT, wkvT, bq, bk, bv,
                                 Qb, Kb, Vtb);
  // 3. attention, s-split=2 -> 1024 blocks, 4 blk/CU
  k_attn<<<dim3(512, 2), 256, 0, stream>>>(Qb, Kb, Vtb, opart, lpart);
  k_actx<<<4096, 256, 0, stream>>>(opart, lpart, ctx);
  // 4. O-proj non-split raw -> opj (16 BK-64 iters; split traffic not worth it)
  k_gemm<64, 128><<<dim3(8, 64, 1), 256, 0, stream>>>(
      ctx, woT, nullptr, nullptr, opj, nullptr,
      4096, 1024, 1024, 1024, 1.0f, 16);
  // 5. LN1 fused combine: y = opj + bo + tgt
  k_lnp<<<4096, 256, 0, stream>>>(opj, 1, bo, tgt, g1, be1, xf, xb);
  // 6. FFN1: relu(x @ w1 + b1), 128x128, 1024 blocks, BK=64
  k_gemm<128, 128><<<dim3(32, 32), 256, 0, stream>>>(
      xb, w1T, b1, nullptr, nullptr, hbuf,
      4096, 4096, 1024, 1024, 1.0f, 1 | 2);
  // 7. FFN2 split-K=2 raw partials -> fp2, BK=64 (32 iters per z)
  k_gemm<64, 128><<<dim3(8, 64, 2), 256, 0, stream>>>(
      hbuf, w2T, nullptr, nullptr, fp2, nullptr,
      4096, 1024, 4096, 2048, 1.0f, 16);
  // 8. LN2 fused combine: y = fp2_0+fp2_1+b2+xf
  k_lnp<<<4096, 256, 0, stream>>>(fp2, 2, b2, xf, g2, be2, out, nullptr);
}